// Round 1
// baseline (1507.671 us; speedup 1.0000x reference)
//
#include <hip/hip_runtime.h>
#include <math.h>

typedef unsigned short u16;
typedef short s16x8 __attribute__((ext_vector_type(8)));
typedef float f32x4 __attribute__((ext_vector_type(4)));

#define GLOAD16(gp, lp)                                                        \
  __builtin_amdgcn_global_load_lds(                                            \
      (const __attribute__((address_space(1))) void*)(gp),                     \
      (__attribute__((address_space(3))) void*)(lp), 16, 0, 0)

__device__ __forceinline__ u16 f2bf(float f) {
  union { float f; unsigned u; } v; v.f = f;
  unsigned r = v.u + 0x7fffu + ((v.u >> 16) & 1u);  // RNE
  return (u16)(r >> 16);
}

// ---------------- kernel 1: x fp32 -> bf16 (same layout) ----------------
__global__ __launch_bounds__(256) void cvt_x_kernel(const float* __restrict__ in,
                                                    u16* __restrict__ out) {
  size_t i = ((size_t)blockIdx.x * 256 + threadIdx.x) * 8;
  float4 a = *(const float4*)(in + i);
  float4 b = *(const float4*)(in + i + 4);
  s16x8 v;
  v[0] = (short)f2bf(a.x); v[1] = (short)f2bf(a.y);
  v[2] = (short)f2bf(a.z); v[3] = (short)f2bf(a.w);
  v[4] = (short)f2bf(b.x); v[5] = (short)f2bf(b.y);
  v[6] = (short)f2bf(b.z); v[7] = (short)f2bf(b.w);
  *(s16x8*)(out + i) = v;
}

// ------- kernel 2: W fp32 [R][C] -> W^T bf16 [C][R], 64x64 tiles -------
__global__ __launch_bounds__(256) void transpose_cvt_kernel(
    const float* __restrict__ in0, const float* __restrict__ in1,
    const float* __restrict__ in2, const float* __restrict__ in3,
    const float* __restrict__ in4, const float* __restrict__ in5,
    u16* __restrict__ o0, u16* __restrict__ o1, u16* __restrict__ o2,
    u16* __restrict__ o3, u16* __restrict__ o4, u16* __restrict__ o5) {
  __shared__ float s[64 * 65];
  const int mat = blockIdx.y;
  const float* in; u16* out;
  switch (mat) {
    case 0: in = in0; out = o0; break;
    case 1: in = in1; out = o1; break;
    case 2: in = in2; out = o2; break;
    case 3: in = in3; out = o3; break;
    case 4: in = in4; out = o4; break;
    default: in = in5; out = o5; break;
  }
  const int R = (mat < 4) ? 4096 : 11008;
  const int C = (mat < 4) ? 11008 : 4096;
  const int nTc = C >> 6;
  const int tr = blockIdx.x / nTc, tc = blockIdx.x - tr * nTc;
  const int r0 = tr << 6, c0 = tc << 6;
  const int t = threadIdx.x;
#pragma unroll
  for (int p = 0; p < 4; ++p) {
    const int lr = p * 16 + (t >> 4);
    const int lc = (t & 15) * 4;
    float4 v = *(const float4*)(in + (size_t)(r0 + lr) * C + (c0 + lc));
    float* sp = &s[lr * 65 + lc];
    sp[0] = v.x; sp[1] = v.y; sp[2] = v.z; sp[3] = v.w;
  }
  __syncthreads();
#pragma unroll
  for (int q = 0; q < 2; ++q) {
    const int oc = q * 32 + (t >> 3);
    const int orr = (t & 7) * 8;
    s16x8 v;
#pragma unroll
    for (int i = 0; i < 8; ++i) v[i] = (short)f2bf(s[(orr + i) * 65 + oc]);
    *(s16x8*)(out + (size_t)(c0 + oc) * R + (r0 + orr)) = v;
  }
}

// ---------------- kernel 3: fused gate+up GEMM + silu*u -> h ----------------
// C tile 128x128, BK=64, 4 waves (2x2), each wave 64x64 = 4x4 frags of 16x16.
// LDS tiles [128 rows][64 k] bf16 with 16B XOR swizzle: byte ^= ((row&7)<<4),
// applied on the GLOBAL source address (global_load_lds writes linearly) and
// on the ds_read address.
__global__ __launch_bounds__(256, 2) void gemm_gateup_kernel(
    const u16* __restrict__ X, const u16* __restrict__ GTl,
    const u16* __restrict__ UTl, const u16* __restrict__ GTv,
    const u16* __restrict__ UTv, const int* __restrict__ tt,
    u16* __restrict__ H) {
  __shared__ u16 sA[128 * 64];
  __shared__ u16 sG[128 * 64];
  __shared__ u16 sU[128 * 64];

  const int mT = blockIdx.x & 31;   // m fastest -> n-major order for B reuse
  const int nT = blockIdx.x >> 5;
  const int t = threadIdx.x;
  const int lane = t & 63;
  const int wr = ((t >> 7) & 1) * 64;
  const int wc = ((t >> 6) & 1) * 64;

  const int side = tt[mT << 7];
  const u16* GT = side ? GTl : GTv;
  const u16* UT = side ? UTl : UTv;

  // staging: chunk = p*256+t covers LDS bytes [chunk*16, +16); row = chunk>>3
  const int swz = (((t & 7) ^ ((t >> 3) & 7)) << 4);
  const char* aP = (const char*)X  + (size_t)((mT << 7) + (t >> 3)) * 8192 + swz;
  const char* gP = (const char*)GT + (size_t)((nT << 7) + (t >> 3)) * 8192 + swz;
  const char* uP = (const char*)UT + (size_t)((nT << 7) + (t >> 3)) * 8192 + swz;
  const int ldsOff = (t & 192) << 4;  // wave-uniform base, HW adds lane*16

  f32x4 accG[4][4], accU[4][4];
  const f32x4 z = {0.f, 0.f, 0.f, 0.f};
#pragma unroll
  for (int i = 0; i < 4; ++i)
#pragma unroll
    for (int j = 0; j < 4; ++j) { accG[i][j] = z; accU[i][j] = z; }

  const int hi16 = ((lane >> 4) << 4);
  const int rsw = (lane & 7) << 4;
  const int rlo = lane & 15;

  for (int kk = 0; kk < 64; ++kk) {
#pragma unroll
    for (int p = 0; p < 4; ++p) {
      GLOAD16(aP + (size_t)p * 262144, (char*)sA + (p << 12) + ldsOff);
      GLOAD16(gP + (size_t)p * 262144, (char*)sG + (p << 12) + ldsOff);
      GLOAD16(uP + (size_t)p * 262144, (char*)sU + (p << 12) + ldsOff);
    }
    aP += 128; gP += 128; uP += 128;
    __syncthreads();  // drains vmcnt -> LDS tiles ready
#pragma unroll
    for (int ks = 0; ks < 2; ++ks) {
      s16x8 af[4], gf[4], uf[4];
      const int kb = (ks << 6) + hi16;
#pragma unroll
      for (int i = 0; i < 4; ++i) {
        const int ra = (wr + i * 16 + rlo) * 128 + (kb ^ rsw);
        af[i] = *(const s16x8*)((const char*)sA + ra);
        const int rb = (wc + i * 16 + rlo) * 128 + (kb ^ rsw);
        gf[i] = *(const s16x8*)((const char*)sG + rb);
        uf[i] = *(const s16x8*)((const char*)sU + rb);
      }
#pragma unroll
      for (int i = 0; i < 4; ++i)
#pragma unroll
        for (int j = 0; j < 4; ++j) {
          accG[i][j] = __builtin_amdgcn_mfma_f32_16x16x32_bf16(af[i], gf[j], accG[i][j], 0, 0, 0);
          accU[i][j] = __builtin_amdgcn_mfma_f32_16x16x32_bf16(af[i], uf[j], accU[i][j], 0, 0, 0);
        }
    }
    __syncthreads();  // everyone done reading before next stage overwrites
  }

  const int r0 = (mT << 7) + wr + ((lane >> 4) << 2);
  const int c0 = (nT << 7) + wc + rlo;
#pragma unroll
  for (int i = 0; i < 4; ++i)
#pragma unroll
    for (int j = 0; j < 4; ++j)
#pragma unroll
      for (int r = 0; r < 4; ++r) {
        const float g = accG[i][j][r];
        const float u = accU[i][j][r];
        const float hv = g / (1.f + __expf(-g)) * u;
        H[(size_t)(r0 + i * 16 + r) * 11008 + (c0 + j * 16)] = f2bf(hv);
      }
}

// ---------------- kernel 4: down GEMM -> out fp32 ----------------
__global__ __launch_bounds__(256, 2) void gemm_down_kernel(
    const u16* __restrict__ H, const u16* __restrict__ DTl,
    const u16* __restrict__ DTv, const int* __restrict__ tt,
    float* __restrict__ out) {
  __shared__ u16 sA[128 * 64];
  __shared__ u16 sB[128 * 64];

  const int mT = blockIdx.x & 31;
  const int nT = blockIdx.x >> 5;
  const int t = threadIdx.x;
  const int lane = t & 63;
  const int wr = ((t >> 7) & 1) * 64;
  const int wc = ((t >> 6) & 1) * 64;

  const int side = tt[mT << 7];
  const u16* DT = side ? DTl : DTv;

  const int swz = (((t & 7) ^ ((t >> 3) & 7)) << 4);
  const char* aP = (const char*)H  + (size_t)((mT << 7) + (t >> 3)) * 22016 + swz;
  const char* bP = (const char*)DT + (size_t)((nT << 7) + (t >> 3)) * 22016 + swz;
  const int ldsOff = (t & 192) << 4;

  f32x4 acc[4][4];
  const f32x4 z = {0.f, 0.f, 0.f, 0.f};
#pragma unroll
  for (int i = 0; i < 4; ++i)
#pragma unroll
    for (int j = 0; j < 4; ++j) acc[i][j] = z;

  const int hi16 = ((lane >> 4) << 4);
  const int rsw = (lane & 7) << 4;
  const int rlo = lane & 15;

  for (int kk = 0; kk < 172; ++kk) {
#pragma unroll
    for (int p = 0; p < 4; ++p) {
      GLOAD16(aP + (size_t)p * 704512, (char*)sA + (p << 12) + ldsOff);
      GLOAD16(bP + (size_t)p * 704512, (char*)sB + (p << 12) + ldsOff);
    }
    aP += 128; bP += 128;
    __syncthreads();
#pragma unroll
    for (int ks = 0; ks < 2; ++ks) {
      s16x8 af[4], bfr[4];
      const int kb = (ks << 6) + hi16;
#pragma unroll
      for (int i = 0; i < 4; ++i) {
        af[i] = *(const s16x8*)((const char*)sA + (wr + i * 16 + rlo) * 128 + (kb ^ rsw));
        bfr[i] = *(const s16x8*)((const char*)sB + (wc + i * 16 + rlo) * 128 + (kb ^ rsw));
      }
#pragma unroll
      for (int i = 0; i < 4; ++i)
#pragma unroll
        for (int j = 0; j < 4; ++j)
          acc[i][j] = __builtin_amdgcn_mfma_f32_16x16x32_bf16(af[i], bfr[j], acc[i][j], 0, 0, 0);
    }
    __syncthreads();
  }

  const int r0 = (mT << 7) + wr + ((lane >> 4) << 2);
  const int c0 = (nT << 7) + wc + rlo;
#pragma unroll
  for (int i = 0; i < 4; ++i)
#pragma unroll
    for (int j = 0; j < 4; ++j)
#pragma unroll
      for (int r = 0; r < 4; ++r)
        out[(size_t)(r0 + i * 16 + r) * 4096 + (c0 + j * 16)] = acc[i][j][r];
}

extern "C" void kernel_launch(void* const* d_in, const int* in_sizes, int n_in,
                              void* d_out, int out_size, void* d_ws, size_t ws_size,
                              hipStream_t stream) {
  (void)in_sizes; (void)n_in; (void)out_size; (void)ws_size;
  const float* x  = (const float*)d_in[0];
  const int*   tt = (const int*)d_in[1];
  const float* lg = (const float*)d_in[2];
  const float* lu = (const float*)d_in[3];
  const float* ld = (const float*)d_in[4];
  const float* vg = (const float*)d_in[5];
  const float* vu = (const float*)d_in[6];
  const float* vd = (const float*)d_in[7];

  u16* ws  = (u16*)d_ws;
  u16* xbf = ws;                      // 4096*4096
  u16* lgT = xbf + 16777216;          // each transposed weight: 11008*4096
  u16* luT = lgT + 45088768;
  u16* vgT = luT + 45088768;
  u16* vuT = vgT + 45088768;
  u16* ldT = vuT + 45088768;
  u16* vdT = ldT + 45088768;
  u16* hbuf = vdT + 45088768;         // 4096*11008
  // total ws use: 332,398,592 u16 = ~665 MB

  cvt_x_kernel<<<dim3(8192), dim3(256), 0, stream>>>(x, xbf);
  transpose_cvt_kernel<<<dim3(11008, 6), dim3(256), 0, stream>>>(
      lg, lu, vg, vu, ld, vd, lgT, luT, vgT, vuT, ldT, vdT);
  gemm_gateup_kernel<<<dim3(2752), dim3(256), 0, stream>>>(
      xbf, lgT, luT, vgT, vuT, tt, hbuf);
  gemm_down_kernel<<<dim3(1024), dim3(256), 0, stream>>>(
      hbuf, ldT, vdT, tt, (float*)d_out);
}